// Round 9
// baseline (1967.683 us; speedup 1.0000x reference)
//
#include <hip/hip_runtime.h>
#include <math.h>

// JacobiConv: y = sum_k comb[k] (.) P_k,  P_k = Jacobi recurrence with L @ P matmuls.
// N=16384, C=32, K=10, A=B=1.
// Round 9: persistent fused kernel for iterations 2..10. One 256-block launch
// (1 block/CU), manual grid barrier between iterations (monotonic counter,
// device-scope atomics + fences for cross-XCD visibility). Per-thread fp32
// poly masters (pp, p2) and y accumulator stay in REGISTERS across all 9
// iterations -> no Pprev/Pnew/y HBM round-trips, no launch gaps.
// GEMM body identical to round 8 (4 row-tiles x 2 col-tiles, ping-pong).

#define NN 16384
#define CC 32
#define KPOLY 10
#define NSPLIT 16
#define NTK (NN / 32)        // 512 k-tiles per 16-row block
#define WTILES 64            // k-tiles per wave (2048 k)
#define NBLK 256             // persistent grid

typedef _Float16 half8 __attribute__((ext_vector_type(8)));
typedef float f32x4 __attribute__((ext_vector_type(4)));
typedef unsigned int u32x4 __attribute__((ext_vector_type(4)));
typedef unsigned int u32x2 __attribute__((ext_vector_type(2)));

union U16 {
  u32x4 u;
  half8 h;
};
union H4 {
  _Float16 h[4];
  u32x2 u;
};

struct Coefs {
  float r1[KPOLY + 1];
  float r2[KPOLY + 1];
  float r3[KPOLY + 1];
};

// ---------------------- L fp32 -> fp16 fragment pack, fused with GEMM for P1
// Lf layout: Lf[((tr*NTK + tk)*64 + lane)*8 + pos] =
//            L[tr*16 + (lane&15)][tk*32 + (lane>>4)*8 + pos]
__global__ __launch_bounds__(256) void conv_pack_gemm1(const float* __restrict__ L,
                                                       _Float16* __restrict__ Lf,
                                                       const _Float16* __restrict__ Ph,
                                                       float* __restrict__ part) {
  __shared__ __align__(16) _Float16 lds[16 * 1024];  // 32 KiB; swizzle u ^= (r&7)
  const int tid = threadIdx.x;
  const int tr = blockIdx.x >> 4;  // row-block 0..1023
  const int sc = blockIdx.x & 15;  // col-slab == split 0..15
  const float* src = L + (size_t)tr * 16 * NN + (size_t)sc * 1024;

#pragma unroll
  for (int j = 0; j < 16; ++j) {
    const int flat = j * 256 + tid;  // 0..4095
    const int r = flat >> 8;         // row 0..15
    const int cu = flat & 255;       // float4 index within row
    f32x4 v = __builtin_nontemporal_load(
        reinterpret_cast<const f32x4*>(src + (size_t)r * NN) + cu);
    H4 o;
    o.h[0] = (_Float16)v.x;
    o.h[1] = (_Float16)v.y;
    o.h[2] = (_Float16)v.z;
    o.h[3] = (_Float16)v.w;
    const int u = (cu >> 1) ^ (r & 7);
    *reinterpret_cast<u32x2*>(&lds[r * 1024 + u * 8 + (cu & 1) * 4]) = o.u;
  }
  __syncthreads();

  const int lane = tid & 63;
  const int wave = tid >> 6;
  const int r = lane & 15;
  const int lg = lane >> 4;

  f32x4 acc0 = (f32x4){0.f, 0.f, 0.f, 0.f};
  f32x4 acc1 = (f32x4){0.f, 0.f, 0.f, 0.f};
#pragma unroll
  for (int i = 0; i < 8; ++i) {
    const int tkl = wave * 8 + i;  // k-tile within slab 0..31
    const int u = (tkl * 4 + lg) ^ (r & 7);
    U16 aval;
    aval.u = *reinterpret_cast<const u32x4*>(&lds[r * 1024 + u * 8]);
    const size_t tk = (size_t)sc * 32 + tkl;
    __builtin_nontemporal_store(
        aval.u, reinterpret_cast<u32x4*>(Lf + ((size_t)tr * NTK + tk) * 512) + lane);
    const int kb = sc * 128 + tkl * 4 + lg;  // 8-elem k-block into Ph
    U16 b0, b1;
    b0.u = *reinterpret_cast<const u32x4*>(Ph + (size_t)kb * 256 + (size_t)r * 8);
    b1.u = *reinterpret_cast<const u32x4*>(Ph + (size_t)kb * 256 + (size_t)(16 + r) * 8);
    acc0 = __builtin_amdgcn_mfma_f32_16x16x32_f16(aval.h, b0.h, acc0, 0, 0, 0);
    acc1 = __builtin_amdgcn_mfma_f32_16x16x32_f16(aval.h, b1.h, acc1, 0, 0, 0);
  }
  __syncthreads();

  float* red = reinterpret_cast<float*>(lds);  // reuse: 4 waves x 512 f32 = 8 KiB
#pragma unroll
  for (int j = 0; j < 4; ++j) {
    red[wave * 512 + (lg * 4 + j) * 32 + r] = acc0[j];
    red[wave * 512 + (lg * 4 + j) * 32 + 16 + r] = acc1[j];
  }
  __syncthreads();

  const int e = tid * 2;  // 256 threads x 2 floats = 512 entries (16 rows x 32 cols)
  float2 s0 = *reinterpret_cast<const float2*>(&red[e]);
  float2 s1 = *reinterpret_cast<const float2*>(&red[512 + e]);
  float2 s2 = *reinterpret_cast<const float2*>(&red[1024 + e]);
  float2 s3 = *reinterpret_cast<const float2*>(&red[1536 + e]);
  float2 s = make_float2(s0.x + s1.x + s2.x + s3.x, s0.y + s1.y + s2.y + s3.y);
  *reinterpret_cast<float2*>(part + (size_t)sc * NN * CC + (size_t)tr * 16 * CC + e) = s;
}

// -------------------------------------------------------------- grid barrier
__device__ __forceinline__ void gridbar(unsigned* cnt, unsigned target) {
  __syncthreads();
  if (threadIdx.x == 0) {
    __threadfence();  // release: flush our writes device-wide
    __hip_atomic_fetch_add(cnt, 1u, __ATOMIC_ACQ_REL, __HIP_MEMORY_SCOPE_AGENT);
    while (__hip_atomic_load(cnt, __ATOMIC_ACQUIRE, __HIP_MEMORY_SCOPE_AGENT) < target) {
      __builtin_amdgcn_s_sleep(8);
    }
    __threadfence();  // acquire: invalidate caches before re-reading Ph
  }
  __syncthreads();
}

// ---------------------------------- persistent fused GEMM + poly, iters 2..10
// Block = 8 waves x 512 threads = 64 rows x K=16384; wave = 4 row-tiles x
// 2 col-tiles x 64 k-tiles. fp32 masters pp/p2 and y accumulator in registers.
__global__ __launch_bounds__(512, 1) void gemm_poly_persist(
    const _Float16* __restrict__ Lf, _Float16* __restrict__ PhA,
    _Float16* __restrict__ PhB, const float* __restrict__ x,
    const float* __restrict__ P1, float* __restrict__ y,
    const float* __restrict__ conv, const float* __restrict__ comb,
    unsigned* __restrict__ cnt, Coefs cf) {
  const int tid = threadIdx.x;
  const int lane = tid & 63;
  const int wave = tid >> 6;
  const int trb = blockIdx.x * 4;  // first 16-row unit
  const int l15 = lane & 15;
  const int lg = lane >> 4;
  const int tk0 = wave * WTILES;

  const u32x4* Ap[4];
#pragma unroll
  for (int rt = 0; rt < 4; ++rt)
    Ap[rt] = reinterpret_cast<const u32x4*>(
                 Lf + ((size_t)(trb + rt) * NTK + tk0) * 512) +
             lane;

  // persistent per-thread poly state (same (n,c) cells every iteration)
  const int e0 = tid * 4;
  const int row = e0 >> 5;
  const int c = e0 & 31;
  const int n = blockIdx.x * 64 + row;
  const size_t g = (size_t)n * CC + c;
  const size_t pb = (size_t)(n >> 3) * 256 + (size_t)c * 8 + (n & 7);
  float4 pp = *reinterpret_cast<const float4*>(P1 + g);
  float4 p2 = *reinterpret_cast<const float4*>(x + g);
  float4 yacc = *reinterpret_cast<const float4*>(y + g);

  __shared__ float red[8][2048];  // 64 KiB

  for (int i = 2; i <= KPOLY; ++i) {
    const _Float16* PhIn = (i & 1) ? PhA : PhB;
    _Float16* PhOut = (i & 1) ? PhB : PhA;
    const _Float16* Bbase = PhIn + (size_t)(tk0 * 4 + lg) * 256 + (size_t)l15 * 8;

    f32x4 acc[4][2];
#pragma unroll
    for (int rt = 0; rt < 4; ++rt)
#pragma unroll
      for (int ct = 0; ct < 2; ++ct) acc[rt][ct] = (f32x4){0.f, 0.f, 0.f, 0.f};

    U16 A[2][4], B[2][2];
#pragma unroll
    for (int rt = 0; rt < 4; ++rt) A[0][rt].u = __builtin_nontemporal_load(Ap[rt]);
#pragma unroll
    for (int ct = 0; ct < 2; ++ct)
      B[0][ct].u = *reinterpret_cast<const u32x4*>(Bbase + ct * 128);

#pragma unroll
    for (int kk = 0; kk < WTILES; ++kk) {
      const int cur = kk & 1;
      const int nxt = cur ^ 1;
      if (kk < WTILES - 1) {
#pragma unroll
        for (int rt = 0; rt < 4; ++rt)
          A[nxt][rt].u = __builtin_nontemporal_load(Ap[rt] + (kk + 1) * 64);
#pragma unroll
        for (int ct = 0; ct < 2; ++ct)
          B[nxt][ct].u = *reinterpret_cast<const u32x4*>(
              Bbase + (size_t)(kk + 1) * 1024 + ct * 128);
      }
#pragma unroll
      for (int rt = 0; rt < 4; ++rt)
#pragma unroll
        for (int ct = 0; ct < 2; ++ct)
          acc[rt][ct] = __builtin_amdgcn_mfma_f32_16x16x32_f16(
              A[cur][rt].h, B[cur][ct].h, acc[rt][ct], 0, 0, 0);
    }

    // 8-way reduce across wave k-segments
#pragma unroll
    for (int rt = 0; rt < 4; ++rt)
#pragma unroll
      for (int ct = 0; ct < 2; ++ct)
#pragma unroll
        for (int j = 0; j < 4; ++j)
          red[wave][(rt * 16 + lg * 4 + j) * 32 + ct * 16 + l15] = acc[rt][ct][j];
    __syncthreads();

    float4 t = make_float4(0.f, 0.f, 0.f, 0.f);
#pragma unroll
    for (int w = 0; w < 8; ++w) {
      float4 p = *reinterpret_cast<const float4*>(&red[w][e0]);
      t.x += p.x;
      t.y += p.y;
      t.z += p.z;
      t.w += p.w;
    }

    const float a1 = 2.f * tanhf(conv[i - 1]);
    const float a2 = 2.f * tanhf(conv[i - 2]);
    const float cL = a1 * cf.r1[i];
    const float cP = a1 * cf.r2[i];
    const float cPP = a1 * a2 * cf.r3[i];

    float4 pn;
    pn.x = cL * t.x + cP * pp.x - cPP * p2.x;
    pn.y = cL * t.y + cP * pp.y - cPP * p2.y;
    pn.z = cL * t.z + cP * pp.z - cPP * p2.z;
    pn.w = cL * t.w + cP * pp.w - cPP * p2.w;

    PhOut[pb] = (_Float16)pn.x;
    PhOut[pb + 8] = (_Float16)pn.y;
    PhOut[pb + 16] = (_Float16)pn.z;
    PhOut[pb + 24] = (_Float16)pn.w;

    const float4 cb = *reinterpret_cast<const float4*>(comb + (size_t)i * CC + c);
    yacc.x = fmaf(cb.x, pn.x, yacc.x);
    yacc.y = fmaf(cb.y, pn.y, yacc.y);
    yacc.z = fmaf(cb.z, pn.z, yacc.z);
    yacc.w = fmaf(cb.w, pn.w, yacc.w);

    p2 = pp;
    pp = pn;

    if (i < KPOLY) gridbar(cnt, (unsigned)(i - 1) * NBLK);
  }

  *reinterpret_cast<float4*>(y + g) = yacc;
}

// ---------------------------------------------------------------- elementwise
// y = comb0 (.) x ; Ph_blk = fp16(x); zero the grid-barrier counter
__global__ __launch_bounds__(256) void init_kernel(const float* __restrict__ x,
                                                   const float* __restrict__ comb,
                                                   float* __restrict__ y,
                                                   _Float16* __restrict__ Ph,
                                                   unsigned* __restrict__ cnt) {
  int idx = blockIdx.x * blockDim.x + threadIdx.x;  // float4 index over N*C/4
  if (idx == 0) __hip_atomic_store(cnt, 0u, __ATOMIC_RELAXED, __HIP_MEMORY_SCOPE_AGENT);
  float4 xv = reinterpret_cast<const float4*>(x)[idx];
  int c4 = (idx & 7) << 2;
  int n = idx >> 3;
  float4 cb = *reinterpret_cast<const float4*>(comb + c4);
  reinterpret_cast<float4*>(y)[idx] =
      make_float4(xv.x * cb.x, xv.y * cb.y, xv.z * cb.z, xv.w * cb.w);
  size_t pbi = (size_t)(n >> 3) * 256 + (size_t)c4 * 8 + (n & 7);
  Ph[pbi] = (_Float16)xv.x;
  Ph[pbi + 8] = (_Float16)xv.y;
  Ph[pbi + 16] = (_Float16)xv.z;
  Ph[pbi + 24] = (_Float16)xv.w;
}

// iter-1 only: t = sum_s part[s]; P1 = cL*t + cP*x; y += comb1 (.) P1;
// PhOut = fp16 blocked(P1)
__global__ __launch_bounds__(256) void poly_update(
    const float* __restrict__ part, float* __restrict__ Pnew,
    const float* __restrict__ Pprev, float* __restrict__ y,
    _Float16* __restrict__ PhOut, const float* __restrict__ conv,
    const float* __restrict__ comb_row, float r1, float r2, int ia) {
  int idx = blockIdx.x * blockDim.x + threadIdx.x;
  float a1 = 2.f * tanhf(conv[ia]);
  float cL = a1 * r1;
  float cP = a1 * r2;

  float4 t = make_float4(0.f, 0.f, 0.f, 0.f);
#pragma unroll
  for (int s = 0; s < NSPLIT; ++s) {
    float4 p = reinterpret_cast<const float4*>(part)[(size_t)s * (NN * CC / 4) + idx];
    t.x += p.x;
    t.y += p.y;
    t.z += p.z;
    t.w += p.w;
  }

  float4 pp = reinterpret_cast<const float4*>(Pprev)[idx];
  float4 pn;
  pn.x = cL * t.x + cP * pp.x;
  pn.y = cL * t.y + cP * pp.y;
  pn.z = cL * t.z + cP * pp.z;
  pn.w = cL * t.w + cP * pp.w;
  reinterpret_cast<float4*>(Pnew)[idx] = pn;

  int c4 = (idx & 7) << 2;
  int n = idx >> 3;
  size_t pbi = (size_t)(n >> 3) * 256 + (size_t)c4 * 8 + (n & 7);
  PhOut[pbi] = (_Float16)pn.x;
  PhOut[pbi + 8] = (_Float16)pn.y;
  PhOut[pbi + 16] = (_Float16)pn.z;
  PhOut[pbi + 24] = (_Float16)pn.w;

  float4 cb = *reinterpret_cast<const float4*>(comb_row + c4);
  float4 yv = reinterpret_cast<float4*>(y)[idx];
  yv.x = fmaf(cb.x, pn.x, yv.x);
  yv.y = fmaf(cb.y, pn.y, yv.y);
  yv.z = fmaf(cb.z, pn.z, yv.z);
  yv.w = fmaf(cb.w, pn.w, yv.w);
  reinterpret_cast<float4*>(y)[idx] = yv;
}

// ---------------------------------------------------------------- host side
static void jacobi_r(int i, double a, double b, float& r1, float& r2, float& r3) {
  double div = 2.0 * i * (i + a + b) * (2.0 * i + a + b - 2.0);
  r1 = (float)((2.0 * i + a + b) * (2.0 * i + a + b - 1.0) * (2.0 * i + a + b - 2.0) / div);
  r2 = (float)((2.0 * i + a + b - 1.0) * (a * a - b * b) / div);
  r3 = (float)(2.0 * (i + a - 1.0) * (i + b - 1.0) * (2.0 * i + a + b) / div);
}

extern "C" void kernel_launch(void* const* d_in, const int* in_sizes, int n_in,
                              void* d_out, int out_size, void* d_ws, size_t ws_size,
                              hipStream_t stream) {
  const float* x = (const float*)d_in[0];
  const float* Lm = (const float*)d_in[1];
  const float* conv = (const float*)d_in[2];
  const float* comb = (const float*)d_in[3];
  float* y = (float*)d_out;
  char* ws = (char*)d_ws;

  // workspace layout (bytes)
  _Float16* Lf = (_Float16*)ws;                                  // 512 MiB
  float* part = (float*)(ws + 536870912ull);                     // 32 MiB
  _Float16* PhA = (_Float16*)(ws + 536870912ull + 33554432ull);  // 1 MiB
  _Float16* PhB = PhA + (size_t)NN * CC;                         // 1 MiB
  float* Pb0 = (float*)(ws + 536870912ull + 33554432ull + 4194304ull);  // 2 MiB
  unsigned* cnt = (unsigned*)(ws + 536870912ull + 33554432ull + 4194304ull + 2097152ull);

  const double Aj = 1.0, Bj = 1.0;
  const int ew_blocks = NN * CC / 4 / 256;  // 512

  Coefs cf;
  for (int i = 0; i <= KPOLY; ++i) {
    cf.r1[i] = cf.r2[i] = cf.r3[i] = 0.f;
    if (i >= 2) jacobi_r(i, Aj, Bj, cf.r1[i], cf.r2[i], cf.r3[i]);
  }

  init_kernel<<<ew_blocks, 256, 0, stream>>>(x, comb, y, PhA, cnt);
  conv_pack_gemm1<<<16384, 256, 0, stream>>>(Lm, Lf, PhA, part);

  // iter 1: reduce partials, produce P1 (Pb0) + PhB
  {
    float r1 = (float)((Aj + Bj + 2.0) / 2.0);
    float r2 = (float)((Aj - Bj) / 2.0);
    poly_update<<<ew_blocks, 256, 0, stream>>>(part, Pb0, x, y, PhB, conv,
                                               comb + CC, r1, r2, 0);
  }

  // iters 2..10 in one persistent dispatch
  gemm_poly_persist<<<NBLK, 512, 0, stream>>>(Lf, PhA, PhB, x, Pb0, y, conv, comb,
                                              cnt, cf);
}

// Round 10
// 1171.423 us; speedup vs baseline: 1.6797x; 1.6797x over previous
//
#include <hip/hip_runtime.h>
#include <math.h>

// JacobiConv: y = sum_k comb[k] (.) P_k,  P_k = Jacobi recurrence with L @ P matmuls.
// N=16384, C=32, K=10, A=B=1.
// Round 10: round-8 structure (fused full-K GEMM+poly, 8 waves x 64 rows, ping-pong
// inner loop) + L3 row partitioning: row-units < 480 (240 MB of Lf) use regular
// loads/stores (allocate + stay resident in the 256 MB Infinity Cache across the
// 9 GEMM sweeps); the rest stay nontemporal (never pollute). Round-9 persistence
// reverted (it spilled: 450 MB scratch writes).

#define NN 16384
#define CC 32
#define KPOLY 10
#define NSPLIT 16
#define NTK (NN / 32)        // 512 k-tiles per 16-row block
#define WTILES 64            // k-tiles per wave in gemm_poly (2048 k)
#define RES_UNITS 480        // 16-row units kept L3-resident (240 MB)
#define RES_BLOCKS 120       // gemm_poly blocks (64 rows each) in resident half

typedef _Float16 half8 __attribute__((ext_vector_type(8)));
typedef float f32x4 __attribute__((ext_vector_type(4)));
typedef unsigned int u32x4 __attribute__((ext_vector_type(4)));
typedef unsigned int u32x2 __attribute__((ext_vector_type(2)));

union U16 {
  u32x4 u;
  half8 h;
};
union H4 {
  _Float16 h[4];
  u32x2 u;
};

// ---------------------- L fp32 -> fp16 fragment pack, fused with GEMM for P1
// Lf layout: Lf[((tr*NTK + tk)*64 + lane)*8 + pos] =
//            L[tr*16 + (lane&15)][tk*32 + (lane>>4)*8 + pos]
__global__ __launch_bounds__(256) void conv_pack_gemm1(const float* __restrict__ L,
                                                       _Float16* __restrict__ Lf,
                                                       const _Float16* __restrict__ Ph,
                                                       float* __restrict__ part) {
  __shared__ __align__(16) _Float16 lds[16 * 1024];  // 32 KiB; swizzle u ^= (r&7)
  const int tid = threadIdx.x;
  const int tr = blockIdx.x >> 4;  // row-block 0..1023
  const int sc = blockIdx.x & 15;  // col-slab == split 0..15
  const float* src = L + (size_t)tr * 16 * NN + (size_t)sc * 1024;

#pragma unroll
  for (int j = 0; j < 16; ++j) {
    const int flat = j * 256 + tid;  // 0..4095
    const int r = flat >> 8;         // row 0..15
    const int cu = flat & 255;       // float4 index within row
    f32x4 v = __builtin_nontemporal_load(
        reinterpret_cast<const f32x4*>(src + (size_t)r * NN) + cu);
    H4 o;
    o.h[0] = (_Float16)v.x;
    o.h[1] = (_Float16)v.y;
    o.h[2] = (_Float16)v.z;
    o.h[3] = (_Float16)v.w;
    const int u = (cu >> 1) ^ (r & 7);
    *reinterpret_cast<u32x2*>(&lds[r * 1024 + u * 8 + (cu & 1) * 4]) = o.u;
  }
  __syncthreads();

  const int lane = tid & 63;
  const int wave = tid >> 6;
  const int r = lane & 15;
  const int lg = lane >> 4;
  const bool resident = (tr < RES_UNITS);

  f32x4 acc0 = (f32x4){0.f, 0.f, 0.f, 0.f};
  f32x4 acc1 = (f32x4){0.f, 0.f, 0.f, 0.f};
#pragma unroll
  for (int i = 0; i < 8; ++i) {
    const int tkl = wave * 8 + i;  // k-tile within slab 0..31
    const int u = (tkl * 4 + lg) ^ (r & 7);
    U16 aval;
    aval.u = *reinterpret_cast<const u32x4*>(&lds[r * 1024 + u * 8]);
    const size_t tk = (size_t)sc * 32 + tkl;
    u32x4* dst = reinterpret_cast<u32x4*>(Lf + ((size_t)tr * NTK + tk) * 512) + lane;
    if (resident) {
      *dst = aval.u;  // allocate in L2/L3 -> seeds residency
    } else {
      __builtin_nontemporal_store(aval.u, dst);
    }
    const int kb = sc * 128 + tkl * 4 + lg;  // 8-elem k-block into Ph
    U16 b0, b1;
    b0.u = *reinterpret_cast<const u32x4*>(Ph + (size_t)kb * 256 + (size_t)r * 8);
    b1.u = *reinterpret_cast<const u32x4*>(Ph + (size_t)kb * 256 + (size_t)(16 + r) * 8);
    acc0 = __builtin_amdgcn_mfma_f32_16x16x32_f16(aval.h, b0.h, acc0, 0, 0, 0);
    acc1 = __builtin_amdgcn_mfma_f32_16x16x32_f16(aval.h, b1.h, acc1, 0, 0, 0);
  }
  __syncthreads();

  float* red = reinterpret_cast<float*>(lds);  // reuse: 4 waves x 512 f32 = 8 KiB
#pragma unroll
  for (int j = 0; j < 4; ++j) {
    red[wave * 512 + (lg * 4 + j) * 32 + r] = acc0[j];
    red[wave * 512 + (lg * 4 + j) * 32 + 16 + r] = acc1[j];
  }
  __syncthreads();

  const int e = tid * 2;  // 256 threads x 2 floats = 512 entries (16 rows x 32 cols)
  float2 s0 = *reinterpret_cast<const float2*>(&red[e]);
  float2 s1 = *reinterpret_cast<const float2*>(&red[512 + e]);
  float2 s2 = *reinterpret_cast<const float2*>(&red[1024 + e]);
  float2 s3 = *reinterpret_cast<const float2*>(&red[1536 + e]);
  float2 s = make_float2(s0.x + s1.x + s2.x + s3.x, s0.y + s1.y + s2.y + s3.y);
  *reinterpret_cast<float2*>(part + (size_t)sc * NN * CC + (size_t)tr * 16 * CC + e) = s;
}

// --------------------------------------------------- GEMM inner loop (templated)
// NT=true: A-stream bypasses caches (nontemporal). NT=false: A-stream allocates
// (L3-resident half). Identical schedule either way.
template <bool NT>
__device__ __forceinline__ void kloop(const u32x4* const Ap[4],
                                      const _Float16* __restrict__ Bbase,
                                      f32x4 acc[4][2]) {
  U16 A[2][4], B[2][2];
#pragma unroll
  for (int rt = 0; rt < 4; ++rt)
    A[0][rt].u = NT ? __builtin_nontemporal_load(Ap[rt]) : *Ap[rt];
#pragma unroll
  for (int ct = 0; ct < 2; ++ct)
    B[0][ct].u = *reinterpret_cast<const u32x4*>(Bbase + ct * 128);

#pragma unroll
  for (int kk = 0; kk < WTILES; ++kk) {
    const int cur = kk & 1;
    const int nxt = cur ^ 1;
    if (kk < WTILES - 1) {
#pragma unroll
      for (int rt = 0; rt < 4; ++rt)
        A[nxt][rt].u = NT ? __builtin_nontemporal_load(Ap[rt] + (kk + 1) * 64)
                          : *(Ap[rt] + (kk + 1) * 64);
#pragma unroll
      for (int ct = 0; ct < 2; ++ct)
        B[nxt][ct].u = *reinterpret_cast<const u32x4*>(
            Bbase + (size_t)(kk + 1) * 1024 + ct * 128);
    }
#pragma unroll
    for (int rt = 0; rt < 4; ++rt)
#pragma unroll
      for (int ct = 0; ct < 2; ++ct)
        acc[rt][ct] = __builtin_amdgcn_mfma_f32_16x16x32_f16(A[cur][rt].h, B[cur][ct].h,
                                                             acc[rt][ct], 0, 0, 0);
  }
}

// ----------------------------------------------- full-K fused GEMM + poly update
// Block = 8 waves x 512 threads = 64 rows x K=16384. Wave w: k-tiles
// [w*64, (w+1)*64), 4 row-tiles x 2 col-tiles, acc[4][2].
__global__ __launch_bounds__(512, 1) void gemm_poly(
    const _Float16* __restrict__ Lf, const _Float16* __restrict__ PhIn,
    const float* __restrict__ Pprev, const float* __restrict__ Pprev2,
    float* __restrict__ Pnew, _Float16* __restrict__ PhOut, float* __restrict__ y,
    const float* __restrict__ conv, const float* __restrict__ comb_row, float r1,
    float r2, float r3, int ia, int ib) {
  const int tid = threadIdx.x;
  const int lane = tid & 63;
  const int wave = tid >> 6;
  const int trb = blockIdx.x * 4;  // first 16-row unit (block covers 4 units)
  const int l15 = lane & 15;
  const int lg = lane >> 4;
  const int tk0 = wave * WTILES;

  const u32x4* Ap[4];
#pragma unroll
  for (int rt = 0; rt < 4; ++rt)
    Ap[rt] = reinterpret_cast<const u32x4*>(
                 Lf + ((size_t)(trb + rt) * NTK + tk0) * 512) +
             lane;
  const _Float16* Bbase = PhIn + (size_t)(tk0 * 4 + lg) * 256 + (size_t)l15 * 8;

  f32x4 acc[4][2];
#pragma unroll
  for (int rt = 0; rt < 4; ++rt)
#pragma unroll
    for (int ct = 0; ct < 2; ++ct) acc[rt][ct] = (f32x4){0.f, 0.f, 0.f, 0.f};

  if (blockIdx.x < RES_BLOCKS) {
    kloop<false>(Ap, Bbase, acc);  // L3-resident half
  } else {
    kloop<true>(Ap, Bbase, acc);   // streaming half
  }

  // 8-way reduce across wave k-segments: red[wave][row_local*32 + c]
  __shared__ float red[8][2048];  // 64 KiB
#pragma unroll
  for (int rt = 0; rt < 4; ++rt)
#pragma unroll
    for (int ct = 0; ct < 2; ++ct)
#pragma unroll
      for (int j = 0; j < 4; ++j)
        red[wave][(rt * 16 + lg * 4 + j) * 32 + ct * 16 + l15] = acc[rt][ct][j];
  __syncthreads();

  // 512 threads x 4 entries (float4 over cols)
  const int e0 = tid * 4;
  float4 t = make_float4(0.f, 0.f, 0.f, 0.f);
#pragma unroll
  for (int w = 0; w < 8; ++w) {
    float4 p = *reinterpret_cast<const float4*>(&red[w][e0]);
    t.x += p.x;
    t.y += p.y;
    t.z += p.z;
    t.w += p.w;
  }

  const int row = e0 >> 5;
  const int c = e0 & 31;
  const int n = blockIdx.x * 64 + row;
  const size_t g = (size_t)n * CC + c;

  const float a1 = 2.f * tanhf(conv[ia]);
  const float a2 = 2.f * tanhf(conv[ib]);
  const float cL = a1 * r1;
  const float cP = a1 * r2;
  const float cPP = a1 * a2 * r3;

  float4 pp = *reinterpret_cast<const float4*>(Pprev + g);
  float4 p2 = *reinterpret_cast<const float4*>(Pprev2 + g);
  float4 pn;
  pn.x = cL * t.x + cP * pp.x - cPP * p2.x;
  pn.y = cL * t.y + cP * pp.y - cPP * p2.y;
  pn.z = cL * t.z + cP * pp.z - cPP * p2.z;
  pn.w = cL * t.w + cP * pp.w - cPP * p2.w;
  *reinterpret_cast<float4*>(Pnew + g) = pn;

  const size_t pb = (size_t)(n >> 3) * 256 + (size_t)c * 8 + (n & 7);
  PhOut[pb] = (_Float16)pn.x;
  PhOut[pb + 8] = (_Float16)pn.y;
  PhOut[pb + 16] = (_Float16)pn.z;
  PhOut[pb + 24] = (_Float16)pn.w;

  float4 cb = *reinterpret_cast<const float4*>(comb_row + c);
  float4 yv = *reinterpret_cast<float4*>(y + g);
  yv.x = fmaf(cb.x, pn.x, yv.x);
  yv.y = fmaf(cb.y, pn.y, yv.y);
  yv.z = fmaf(cb.z, pn.z, yv.z);
  yv.w = fmaf(cb.w, pn.w, yv.w);
  *reinterpret_cast<float4*>(y + g) = yv;
}

// ---------------------------------------------------------------- elementwise
// y = comb0 (.) x ; Ph_blk = fp16(x)
__global__ __launch_bounds__(256) void init_kernel(const float* __restrict__ x,
                                                   const float* __restrict__ comb,
                                                   float* __restrict__ y,
                                                   _Float16* __restrict__ Ph) {
  int idx = blockIdx.x * blockDim.x + threadIdx.x;  // float4 index over N*C/4
  float4 xv = reinterpret_cast<const float4*>(x)[idx];
  int c4 = (idx & 7) << 2;
  int n = idx >> 3;
  float4 cb = *reinterpret_cast<const float4*>(comb + c4);
  reinterpret_cast<float4*>(y)[idx] =
      make_float4(xv.x * cb.x, xv.y * cb.y, xv.z * cb.z, xv.w * cb.w);
  size_t pb = (size_t)(n >> 3) * 256 + (size_t)c4 * 8 + (n & 7);
  Ph[pb] = (_Float16)xv.x;
  Ph[pb + 8] = (_Float16)xv.y;
  Ph[pb + 16] = (_Float16)xv.z;
  Ph[pb + 24] = (_Float16)xv.w;
}

// iter-1 only: t = sum_s part[s]; Pnew = cL*t + cP*Pprev; y += comb (.) Pnew;
// PhOut = fp16 blocked(Pnew)
__global__ __launch_bounds__(256) void poly_update(
    const float* __restrict__ part, float* __restrict__ Pnew,
    const float* __restrict__ Pprev, float* __restrict__ y,
    _Float16* __restrict__ PhOut, const float* __restrict__ conv,
    const float* __restrict__ comb_row, float r1, float r2, int ia) {
  int idx = blockIdx.x * blockDim.x + threadIdx.x;
  float a1 = 2.f * tanhf(conv[ia]);
  float cL = a1 * r1;
  float cP = a1 * r2;

  float4 t = make_float4(0.f, 0.f, 0.f, 0.f);
#pragma unroll
  for (int s = 0; s < NSPLIT; ++s) {
    float4 p = reinterpret_cast<const float4*>(part)[(size_t)s * (NN * CC / 4) + idx];
    t.x += p.x;
    t.y += p.y;
    t.z += p.z;
    t.w += p.w;
  }

  float4 pp = reinterpret_cast<const float4*>(Pprev)[idx];
  float4 pn;
  pn.x = cL * t.x + cP * pp.x;
  pn.y = cL * t.y + cP * pp.y;
  pn.z = cL * t.z + cP * pp.z;
  pn.w = cL * t.w + cP * pp.w;
  reinterpret_cast<float4*>(Pnew)[idx] = pn;

  int c4 = (idx & 7) << 2;
  int n = idx >> 3;
  size_t pb = (size_t)(n >> 3) * 256 + (size_t)c4 * 8 + (n & 7);
  PhOut[pb] = (_Float16)pn.x;
  PhOut[pb + 8] = (_Float16)pn.y;
  PhOut[pb + 16] = (_Float16)pn.z;
  PhOut[pb + 24] = (_Float16)pn.w;

  float4 cb = *reinterpret_cast<const float4*>(comb_row + c4);
  float4 yv = reinterpret_cast<float4*>(y)[idx];
  yv.x = fmaf(cb.x, pn.x, yv.x);
  yv.y = fmaf(cb.y, pn.y, yv.y);
  yv.z = fmaf(cb.z, pn.z, yv.z);
  yv.w = fmaf(cb.w, pn.w, yv.w);
  reinterpret_cast<float4*>(y)[idx] = yv;
}

// ---------------------------------------------------------------- host side
static void jacobi_r(int i, double a, double b, float& r1, float& r2, float& r3) {
  double div = 2.0 * i * (i + a + b) * (2.0 * i + a + b - 2.0);
  r1 = (float)((2.0 * i + a + b) * (2.0 * i + a + b - 1.0) * (2.0 * i + a + b - 2.0) / div);
  r2 = (float)((2.0 * i + a + b - 1.0) * (a * a - b * b) / div);
  r3 = (float)(2.0 * (i + a - 1.0) * (i + b - 1.0) * (2.0 * i + a + b) / div);
}

extern "C" void kernel_launch(void* const* d_in, const int* in_sizes, int n_in,
                              void* d_out, int out_size, void* d_ws, size_t ws_size,
                              hipStream_t stream) {
  const float* x = (const float*)d_in[0];
  const float* Lm = (const float*)d_in[1];
  const float* conv = (const float*)d_in[2];
  const float* comb = (const float*)d_in[3];
  float* y = (float*)d_out;
  char* ws = (char*)d_ws;

  // workspace layout (bytes)
  _Float16* Lf = (_Float16*)ws;                                  // 512 MiB
  float* part = (float*)(ws + 536870912ull);                     // 32 MiB
  _Float16* PhA = (_Float16*)(ws + 536870912ull + 33554432ull);  // 1 MiB
  _Float16* PhB = PhA + (size_t)NN * CC;                         // 1 MiB
  float* Pb0 = (float*)(ws + 536870912ull + 33554432ull + 4194304ull);
  float* Pb1 = Pb0 + (size_t)NN * CC;
  float* Pb2 = Pb1 + (size_t)NN * CC;
  float* bufs[3] = {Pb0, Pb1, Pb2};

  const double Aj = 1.0, Bj = 1.0;
  const int ew_blocks = NN * CC / 4 / 256;  // 512

  init_kernel<<<ew_blocks, 256, 0, stream>>>(x, comb, y, PhA);  // PhA = fp16(x)
  conv_pack_gemm1<<<16384, 256, 0, stream>>>(Lm, Lf, PhA, part);

  // iter 1: reduce partials, produce P1 (Pb0) + PhB
  {
    float r1 = (float)((Aj + Bj + 2.0) / 2.0);
    float r2 = (float)((Aj - Bj) / 2.0);
    poly_update<<<ew_blocks, 256, 0, stream>>>(part, bufs[0], x, y, PhB, conv,
                                               comb + CC, r1, r2, 0);
  }

  const float* Pprev = bufs[0];
  const float* Pprev2 = x;
  for (int i = 2; i <= KPOLY; ++i) {
    float r1, r2, r3;
    jacobi_r(i, Aj, Bj, r1, r2, r3);
    float* Pn = bufs[(i - 1) % 3];
    const _Float16* PhIn = (i & 1) ? PhA : PhB;  // i even reads PhB
    _Float16* PhOut = (i & 1) ? PhB : PhA;
    gemm_poly<<<NN / 64, 512, 0, stream>>>(Lf, PhIn, Pprev, Pprev2, Pn, PhOut, y,
                                           conv, comb + (size_t)i * CC, r1, r2, r3,
                                           i - 1, i - 2);
    Pprev2 = Pprev;
    Pprev = Pn;
  }
}

// Round 11
// 1126.957 us; speedup vs baseline: 1.7460x; 1.0395x over previous
//
#include <hip/hip_runtime.h>
#include <math.h>

// JacobiConv: y = sum_k comb[k] (.) P_k,  P_k = Jacobi recurrence with L @ P matmuls.
// N=16384, C=32, K=10, A=B=1.
// Round 11: revert to the proven round-8 configuration (best measured: 1127 us).
// - conv_pack_gemm1: fp32 L -> fp16 fragment-packed Lf, fused with GEMM #1
//   (split-K=16 via col-slabs; LDS gather value IS the MFMA A-fragment).
// - gemm_poly (x9): fused full-K GEMM + Jacobi update + y RMW + fp16 Ph repack.
//   Block = 8 waves x 512 threads = 64 rows x K=16384; wave = 4 row-tiles x
//   2 col-tiles x 64 k-tiles, ping-pong prefetch, nontemporal A-stream.
// L3 partitioning (round 10) removed: MALL ignores nt and its random replacement
// already gives ~50% hits; software residency control is not available.
// Persistence (round 9) removed: register spill (450 MB scratch/dispatch).
// This sits ~3% above the algorithmic HBM floor (10 unavoidable L streams).

#define NN 16384
#define CC 32
#define KPOLY 10
#define NSPLIT 16
#define NTK (NN / 32)        // 512 k-tiles per 16-row block
#define WTILES 64            // k-tiles per wave in gemm_poly (2048 k)

typedef _Float16 half8 __attribute__((ext_vector_type(8)));
typedef float f32x4 __attribute__((ext_vector_type(4)));
typedef unsigned int u32x4 __attribute__((ext_vector_type(4)));
typedef unsigned int u32x2 __attribute__((ext_vector_type(2)));

union U16 {
  u32x4 u;
  half8 h;
};
union H4 {
  _Float16 h[4];
  u32x2 u;
};

// ---------------------- L fp32 -> fp16 fragment pack, fused with GEMM for P1
// Lf layout: Lf[((tr*NTK + tk)*64 + lane)*8 + pos] =
//            L[tr*16 + (lane&15)][tk*32 + (lane>>4)*8 + pos]
__global__ __launch_bounds__(256) void conv_pack_gemm1(const float* __restrict__ L,
                                                       _Float16* __restrict__ Lf,
                                                       const _Float16* __restrict__ Ph,
                                                       float* __restrict__ part) {
  __shared__ __align__(16) _Float16 lds[16 * 1024];  // 32 KiB; swizzle u ^= (r&7)
  const int tid = threadIdx.x;
  const int tr = blockIdx.x >> 4;  // row-block 0..1023
  const int sc = blockIdx.x & 15;  // col-slab == split 0..15
  const float* src = L + (size_t)tr * 16 * NN + (size_t)sc * 1024;

#pragma unroll
  for (int j = 0; j < 16; ++j) {
    const int flat = j * 256 + tid;  // 0..4095
    const int r = flat >> 8;         // row 0..15
    const int cu = flat & 255;       // float4 index within row
    f32x4 v = __builtin_nontemporal_load(
        reinterpret_cast<const f32x4*>(src + (size_t)r * NN) + cu);
    H4 o;
    o.h[0] = (_Float16)v.x;
    o.h[1] = (_Float16)v.y;
    o.h[2] = (_Float16)v.z;
    o.h[3] = (_Float16)v.w;
    const int u = (cu >> 1) ^ (r & 7);
    *reinterpret_cast<u32x2*>(&lds[r * 1024 + u * 8 + (cu & 1) * 4]) = o.u;
  }
  __syncthreads();

  const int lane = tid & 63;
  const int wave = tid >> 6;
  const int r = lane & 15;
  const int lg = lane >> 4;

  f32x4 acc0 = (f32x4){0.f, 0.f, 0.f, 0.f};
  f32x4 acc1 = (f32x4){0.f, 0.f, 0.f, 0.f};
#pragma unroll
  for (int i = 0; i < 8; ++i) {
    const int tkl = wave * 8 + i;  // k-tile within slab 0..31
    const int u = (tkl * 4 + lg) ^ (r & 7);
    U16 aval;
    aval.u = *reinterpret_cast<const u32x4*>(&lds[r * 1024 + u * 8]);
    const size_t tk = (size_t)sc * 32 + tkl;
    __builtin_nontemporal_store(
        aval.u, reinterpret_cast<u32x4*>(Lf + ((size_t)tr * NTK + tk) * 512) + lane);
    const int kb = sc * 128 + tkl * 4 + lg;  // 8-elem k-block into Ph
    U16 b0, b1;
    b0.u = *reinterpret_cast<const u32x4*>(Ph + (size_t)kb * 256 + (size_t)r * 8);
    b1.u = *reinterpret_cast<const u32x4*>(Ph + (size_t)kb * 256 + (size_t)(16 + r) * 8);
    acc0 = __builtin_amdgcn_mfma_f32_16x16x32_f16(aval.h, b0.h, acc0, 0, 0, 0);
    acc1 = __builtin_amdgcn_mfma_f32_16x16x32_f16(aval.h, b1.h, acc1, 0, 0, 0);
  }
  __syncthreads();

  float* red = reinterpret_cast<float*>(lds);  // reuse: 4 waves x 512 f32 = 8 KiB
#pragma unroll
  for (int j = 0; j < 4; ++j) {
    red[wave * 512 + (lg * 4 + j) * 32 + r] = acc0[j];
    red[wave * 512 + (lg * 4 + j) * 32 + 16 + r] = acc1[j];
  }
  __syncthreads();

  const int e = tid * 2;  // 256 threads x 2 floats = 512 entries (16 rows x 32 cols)
  float2 s0 = *reinterpret_cast<const float2*>(&red[e]);
  float2 s1 = *reinterpret_cast<const float2*>(&red[512 + e]);
  float2 s2 = *reinterpret_cast<const float2*>(&red[1024 + e]);
  float2 s3 = *reinterpret_cast<const float2*>(&red[1536 + e]);
  float2 s = make_float2(s0.x + s1.x + s2.x + s3.x, s0.y + s1.y + s2.y + s3.y);
  *reinterpret_cast<float2*>(part + (size_t)sc * NN * CC + (size_t)tr * 16 * CC + e) = s;
}

// ----------------------------------------------- full-K fused GEMM + poly update
// Block = 8 waves x 512 threads = 64 rows x K=16384. Wave w: k-tiles
// [w*64, (w+1)*64), 4 row-tiles x 2 col-tiles, acc[4][2] (round-6 density).
// 8-way LDS reduce; epilogue: Pnew = cL*t + cP*Pprev - cPP*Pprev2; y += comb.Pnew;
// PhOut = blocked fp16(Pnew).
__global__ __launch_bounds__(512, 1) void gemm_poly(
    const _Float16* __restrict__ Lf, const _Float16* __restrict__ PhIn,
    const float* __restrict__ Pprev, const float* __restrict__ Pprev2,
    float* __restrict__ Pnew, _Float16* __restrict__ PhOut, float* __restrict__ y,
    const float* __restrict__ conv, const float* __restrict__ comb_row, float r1,
    float r2, float r3, int ia, int ib) {
  const int tid = threadIdx.x;
  const int lane = tid & 63;
  const int wave = tid >> 6;
  const int trb = blockIdx.x * 4;  // first 16-row unit (block covers 4 units)
  const int l15 = lane & 15;
  const int lg = lane >> 4;
  const int tk0 = wave * WTILES;

  const u32x4* Ap[4];
#pragma unroll
  for (int rt = 0; rt < 4; ++rt)
    Ap[rt] = reinterpret_cast<const u32x4*>(
                 Lf + ((size_t)(trb + rt) * NTK + tk0) * 512) +
             lane;
  const _Float16* Bbase = PhIn + (size_t)(tk0 * 4 + lg) * 256 + (size_t)l15 * 8;

  f32x4 acc[4][2];
#pragma unroll
  for (int rt = 0; rt < 4; ++rt)
#pragma unroll
    for (int ct = 0; ct < 2; ++ct) acc[rt][ct] = (f32x4){0.f, 0.f, 0.f, 0.f};

  U16 A[2][4], B[2][2];
#pragma unroll
  for (int rt = 0; rt < 4; ++rt) A[0][rt].u = __builtin_nontemporal_load(Ap[rt]);
#pragma unroll
  for (int ct = 0; ct < 2; ++ct)
    B[0][ct].u = *reinterpret_cast<const u32x4*>(Bbase + ct * 128);

#pragma unroll
  for (int kk = 0; kk < WTILES; ++kk) {
    const int cur = kk & 1;
    const int nxt = cur ^ 1;
    if (kk < WTILES - 1) {
#pragma unroll
      for (int rt = 0; rt < 4; ++rt)
        A[nxt][rt].u = __builtin_nontemporal_load(Ap[rt] + (kk + 1) * 64);
#pragma unroll
      for (int ct = 0; ct < 2; ++ct)
        B[nxt][ct].u = *reinterpret_cast<const u32x4*>(
            Bbase + (size_t)(kk + 1) * 1024 + ct * 128);
    }
#pragma unroll
    for (int rt = 0; rt < 4; ++rt)
#pragma unroll
      for (int ct = 0; ct < 2; ++ct)
        acc[rt][ct] = __builtin_amdgcn_mfma_f32_16x16x32_f16(A[cur][rt].h, B[cur][ct].h,
                                                             acc[rt][ct], 0, 0, 0);
  }

  // 8-way reduce across wave k-segments: red[wave][row_local*32 + c]
  __shared__ float red[8][2048];  // 64 KiB
#pragma unroll
  for (int rt = 0; rt < 4; ++rt)
#pragma unroll
    for (int ct = 0; ct < 2; ++ct)
#pragma unroll
      for (int j = 0; j < 4; ++j)
        red[wave][(rt * 16 + lg * 4 + j) * 32 + ct * 16 + l15] = acc[rt][ct][j];
  __syncthreads();

  // 512 threads x 4 entries (float4 over cols)
  const int e0 = tid * 4;
  float4 t = make_float4(0.f, 0.f, 0.f, 0.f);
#pragma unroll
  for (int w = 0; w < 8; ++w) {
    float4 p = *reinterpret_cast<const float4*>(&red[w][e0]);
    t.x += p.x;
    t.y += p.y;
    t.z += p.z;
    t.w += p.w;
  }

  const int row = e0 >> 5;
  const int c = e0 & 31;
  const int n = blockIdx.x * 64 + row;
  const size_t g = (size_t)n * CC + c;

  const float a1 = 2.f * tanhf(conv[ia]);
  const float a2 = 2.f * tanhf(conv[ib]);
  const float cL = a1 * r1;
  const float cP = a1 * r2;
  const float cPP = a1 * a2 * r3;

  float4 pp = *reinterpret_cast<const float4*>(Pprev + g);
  float4 p2 = *reinterpret_cast<const float4*>(Pprev2 + g);
  float4 pn;
  pn.x = cL * t.x + cP * pp.x - cPP * p2.x;
  pn.y = cL * t.y + cP * pp.y - cPP * p2.y;
  pn.z = cL * t.z + cP * pp.z - cPP * p2.z;
  pn.w = cL * t.w + cP * pp.w - cPP * p2.w;
  *reinterpret_cast<float4*>(Pnew + g) = pn;

  const size_t pb = (size_t)(n >> 3) * 256 + (size_t)c * 8 + (n & 7);
  PhOut[pb] = (_Float16)pn.x;
  PhOut[pb + 8] = (_Float16)pn.y;
  PhOut[pb + 16] = (_Float16)pn.z;
  PhOut[pb + 24] = (_Float16)pn.w;

  float4 cb = *reinterpret_cast<const float4*>(comb_row + c);
  float4 yv = *reinterpret_cast<float4*>(y + g);
  yv.x = fmaf(cb.x, pn.x, yv.x);
  yv.y = fmaf(cb.y, pn.y, yv.y);
  yv.z = fmaf(cb.z, pn.z, yv.z);
  yv.w = fmaf(cb.w, pn.w, yv.w);
  *reinterpret_cast<float4*>(y + g) = yv;
}

// ---------------------------------------------------------------- elementwise
// y = comb0 (.) x ; Ph_blk = fp16(x)
__global__ __launch_bounds__(256) void init_kernel(const float* __restrict__ x,
                                                   const float* __restrict__ comb,
                                                   float* __restrict__ y,
                                                   _Float16* __restrict__ Ph) {
  int idx = blockIdx.x * blockDim.x + threadIdx.x;  // float4 index over N*C/4
  float4 xv = reinterpret_cast<const float4*>(x)[idx];
  int c4 = (idx & 7) << 2;
  int n = idx >> 3;
  float4 cb = *reinterpret_cast<const float4*>(comb + c4);
  reinterpret_cast<float4*>(y)[idx] =
      make_float4(xv.x * cb.x, xv.y * cb.y, xv.z * cb.z, xv.w * cb.w);
  size_t pb = (size_t)(n >> 3) * 256 + (size_t)c4 * 8 + (n & 7);
  Ph[pb] = (_Float16)xv.x;
  Ph[pb + 8] = (_Float16)xv.y;
  Ph[pb + 16] = (_Float16)xv.z;
  Ph[pb + 24] = (_Float16)xv.w;
}

// iter-1 only: t = sum_s part[s]; Pnew = cL*t + cP*Pprev; y += comb (.) Pnew;
// PhOut = fp16 blocked(Pnew)
__global__ __launch_bounds__(256) void poly_update(
    const float* __restrict__ part, float* __restrict__ Pnew,
    const float* __restrict__ Pprev, float* __restrict__ y,
    _Float16* __restrict__ PhOut, const float* __restrict__ conv,
    const float* __restrict__ comb_row, float r1, float r2, int ia) {
  int idx = blockIdx.x * blockDim.x + threadIdx.x;
  float a1 = 2.f * tanhf(conv[ia]);
  float cL = a1 * r1;
  float cP = a1 * r2;

  float4 t = make_float4(0.f, 0.f, 0.f, 0.f);
#pragma unroll
  for (int s = 0; s < NSPLIT; ++s) {
    float4 p = reinterpret_cast<const float4*>(part)[(size_t)s * (NN * CC / 4) + idx];
    t.x += p.x;
    t.y += p.y;
    t.z += p.z;
    t.w += p.w;
  }

  float4 pp = reinterpret_cast<const float4*>(Pprev)[idx];
  float4 pn;
  pn.x = cL * t.x + cP * pp.x;
  pn.y = cL * t.y + cP * pp.y;
  pn.z = cL * t.z + cP * pp.z;
  pn.w = cL * t.w + cP * pp.w;
  reinterpret_cast<float4*>(Pnew)[idx] = pn;

  int c4 = (idx & 7) << 2;
  int n = idx >> 3;
  size_t pb = (size_t)(n >> 3) * 256 + (size_t)c4 * 8 + (n & 7);
  PhOut[pb] = (_Float16)pn.x;
  PhOut[pb + 8] = (_Float16)pn.y;
  PhOut[pb + 16] = (_Float16)pn.z;
  PhOut[pb + 24] = (_Float16)pn.w;

  float4 cb = *reinterpret_cast<const float4*>(comb_row + c4);
  float4 yv = reinterpret_cast<float4*>(y)[idx];
  yv.x = fmaf(cb.x, pn.x, yv.x);
  yv.y = fmaf(cb.y, pn.y, yv.y);
  yv.z = fmaf(cb.z, pn.z, yv.z);
  yv.w = fmaf(cb.w, pn.w, yv.w);
  reinterpret_cast<float4*>(y)[idx] = yv;
}

// ---------------------------------------------------------------- host side
static void jacobi_r(int i, double a, double b, float& r1, float& r2, float& r3) {
  double div = 2.0 * i * (i + a + b) * (2.0 * i + a + b - 2.0);
  r1 = (float)((2.0 * i + a + b) * (2.0 * i + a + b - 1.0) * (2.0 * i + a + b - 2.0) / div);
  r2 = (float)((2.0 * i + a + b - 1.0) * (a * a - b * b) / div);
  r3 = (float)(2.0 * (i + a - 1.0) * (i + b - 1.0) * (2.0 * i + a + b) / div);
}

extern "C" void kernel_launch(void* const* d_in, const int* in_sizes, int n_in,
                              void* d_out, int out_size, void* d_ws, size_t ws_size,
                              hipStream_t stream) {
  const float* x = (const float*)d_in[0];
  const float* Lm = (const float*)d_in[1];
  const float* conv = (const float*)d_in[2];
  const float* comb = (const float*)d_in[3];
  float* y = (float*)d_out;
  char* ws = (char*)d_ws;

  // workspace layout (bytes)
  _Float16* Lf = (_Float16*)ws;                                  // 512 MiB
  float* part = (float*)(ws + 536870912ull);                     // 32 MiB
  _Float16* PhA = (_Float16*)(ws + 536870912ull + 33554432ull);  // 1 MiB
  _Float16* PhB = PhA + (size_t)NN * CC;                         // 1 MiB
  float* Pb0 = (float*)(ws + 536870912ull + 33554432ull + 4194304ull);
  float* Pb1 = Pb0 + (size_t)NN * CC;
  float* Pb2 = Pb1 + (size_t)NN * CC;
  float* bufs[3] = {Pb0, Pb1, Pb2};

  const double Aj = 1.0, Bj = 1.0;
  const int ew_blocks = NN * CC / 4 / 256;  // 512

  init_kernel<<<ew_blocks, 256, 0, stream>>>(x, comb, y, PhA);  // PhA = fp16(x)
  conv_pack_gemm1<<<16384, 256, 0, stream>>>(Lm, Lf, PhA, part);

  // iter 1: reduce partials, produce P1 (Pb0) + PhB
  {
    float r1 = (float)((Aj + Bj + 2.0) / 2.0);
    float r2 = (float)((Aj - Bj) / 2.0);
    poly_update<<<ew_blocks, 256, 0, stream>>>(part, bufs[0], x, y, PhB, conv,
                                               comb + CC, r1, r2, 0);
  }

  const float* Pprev = bufs[0];
  const float* Pprev2 = x;
  for (int i = 2; i <= KPOLY; ++i) {
    float r1, r2, r3;
    jacobi_r(i, Aj, Bj, r1, r2, r3);
    float* Pn = bufs[(i - 1) % 3];
    const _Float16* PhIn = (i & 1) ? PhA : PhB;  // i even reads PhB
    _Float16* PhOut = (i & 1) ? PhB : PhA;
    gemm_poly<<<NN / 64, 512, 0, stream>>>(Lf, PhIn, Pprev, Pprev2, Pn, PhOut, y,
                                           conv, comb + (size_t)i * CC, r1, r2, r3,
                                           i - 1, i - 2);
    Pprev2 = Pprev;
    Pprev = Pn;
  }
}